// Round 2
// baseline (7496.603 us; speedup 1.0000x reference)
//
#include <hip/hip_runtime.h>
#include <math.h>

// TransformerBlock: B=8, N=1024, D=768, H=12, hd=64, HIDDEN=3072, EPS=1e-6
// All tensors fp32 (per reference). fp32 math throughout.

#define DIM 768
#define SEQ 1024
#define BATCH 8
#define NHEAD 12
#define HDIM 64
#define HID 3072
#define MTOK (BATCH * SEQ)   // 8192

// ---------------- LayerNorm ----------------
__global__ __launch_bounds__(256) void ln_kernel(const float* __restrict__ x,
                                                 const float* __restrict__ scale,
                                                 const float* __restrict__ bias,
                                                 float* __restrict__ y) {
  const int row = blockIdx.x;
  const int t = threadIdx.x;
  const float* xr = x + (size_t)row * DIM;
  float v[3];
  float s1 = 0.f, s2 = 0.f;
#pragma unroll
  for (int j = 0; j < 3; ++j) {
    v[j] = xr[t + j * 256];
    s1 += v[j];
    s2 += v[j] * v[j];
  }
#pragma unroll
  for (int off = 32; off; off >>= 1) {
    s1 += __shfl_down(s1, off, 64);
    s2 += __shfl_down(s2, off, 64);
  }
  __shared__ float r1[4], r2[4], bc[2];
  const int wave = t >> 6, lane = t & 63;
  if (lane == 0) { r1[wave] = s1; r2[wave] = s2; }
  __syncthreads();
  if (t == 0) {
    float S1 = r1[0] + r1[1] + r1[2] + r1[3];
    float S2 = r2[0] + r2[1] + r2[2] + r2[3];
    float mu = S1 * (1.0f / DIM);
    float var = S2 * (1.0f / DIM) - mu * mu;
    bc[0] = mu;
    bc[1] = rsqrtf(fmaxf(var, 0.f) + 1e-6f);
  }
  __syncthreads();
  const float mu = bc[0], rstd = bc[1];
#pragma unroll
  for (int j = 0; j < 3; ++j) {
    const int idx = t + j * 256;
    float o = (v[j] - mu) * rstd * scale[idx] + bias[idx];
    y[(size_t)row * DIM + idx] = o;
  }
}

// ---------------- GEMM: C[M,N] = act(A[M,K] @ W[K,N] + bias) (+ res) ----------------
__device__ __forceinline__ float gelu_tanh(float x) {
  float x3 = x * x * x;
  return 0.5f * x * (1.0f + tanhf(0.7978845608028654f * (x + 0.044715f * x3)));
}

template <int ACT, bool RES>
__global__ __launch_bounds__(256) void gemm_kernel(const float* __restrict__ A,
                                                   const float* __restrict__ W,
                                                   const float* __restrict__ bias,
                                                   const float* __restrict__ res,
                                                   float* __restrict__ C,
                                                   int M, int N, int K) {
  __shared__ float As[16][64];
  __shared__ float Bs[16][65];   // +1 pad
  const int tx = threadIdx.x, ty = threadIdx.y;
  const int t = ty * 16 + tx;
  const int m0 = blockIdx.y * 64, n0 = blockIdx.x * 64;
  float c[4][4] = {};
  for (int k0 = 0; k0 < K; k0 += 16) {
    {
      const int ra = t >> 2, ka = (t & 3) * 4;
      const float4 av = *(const float4*)(A + (size_t)(m0 + ra) * K + k0 + ka);
      As[ka + 0][ra] = av.x;
      As[ka + 1][ra] = av.y;
      As[ka + 2][ra] = av.z;
      As[ka + 3][ra] = av.w;
      const int rb = t >> 4, cb = (t & 15) * 4;
      const float4 bv = *(const float4*)(W + (size_t)(k0 + rb) * N + n0 + cb);
      Bs[rb][cb + 0] = bv.x;
      Bs[rb][cb + 1] = bv.y;
      Bs[rb][cb + 2] = bv.z;
      Bs[rb][cb + 3] = bv.w;
    }
    __syncthreads();
#pragma unroll
    for (int kk = 0; kk < 16; ++kk) {
      float a[4], bb[4];
#pragma unroll
      for (int i = 0; i < 4; ++i) a[i] = As[kk][ty * 4 + i];
#pragma unroll
      for (int j = 0; j < 4; ++j) bb[j] = Bs[kk][tx * 4 + j];
#pragma unroll
      for (int i = 0; i < 4; ++i)
#pragma unroll
        for (int j = 0; j < 4; ++j) c[i][j] += a[i] * bb[j];
    }
    __syncthreads();
  }
#pragma unroll
  for (int i = 0; i < 4; ++i) {
    const int row = m0 + ty * 4 + i;
#pragma unroll
    for (int j = 0; j < 4; ++j) {
      const int col = n0 + tx * 4 + j;
      float v = c[i][j] + bias[col];
      if (ACT == 1) v = gelu_tanh(v);
      if (RES) v += res[(size_t)row * N + col];
      C[(size_t)row * N + col] = v;
    }
  }
}

// ---------------- Attention: one block per (q-row, b*h) ----------------
// qkv layout: [8192, 2304]; cols 0..767=Q, 768..1535=K, 1536..2303=V; head h at h*64.
__global__ __launch_bounds__(256) void attn_kernel(const float* __restrict__ qkv,
                                                   float* __restrict__ o) {
  const int qi = blockIdx.x;           // 0..1023
  const int bh = blockIdx.y;           // 0..95
  const int b = bh / NHEAD, h = bh % NHEAD;
  const int t = threadIdx.x;

  __shared__ float qsh[HDIM];
  __shared__ float sc[SEQ];
  __shared__ float red[5];
  __shared__ float opart[4][HDIM];

  const size_t rowQ = (size_t)(b * SEQ + qi) * (3 * DIM);
  if (t < HDIM) qsh[t] = qkv[rowQ + h * HDIM + t];
  __syncthreads();

  // scores
  float lmax = -1e30f;
  const size_t kbase = (size_t)(b * SEQ) * (3 * DIM) + DIM + h * HDIM;
#pragma unroll
  for (int j = 0; j < 4; ++j) {
    const int k = t + j * 256;
    const float* kr = qkv + kbase + (size_t)k * (3 * DIM);
    float acc = 0.f;
#pragma unroll
    for (int d = 0; d < HDIM; d += 4) {
      const float4 kv = *(const float4*)(kr + d);
      acc += qsh[d] * kv.x + qsh[d + 1] * kv.y + qsh[d + 2] * kv.z + qsh[d + 3] * kv.w;
    }
    acc *= 0.125f;  // hd^-0.5
    sc[k] = acc;
    lmax = fmaxf(lmax, acc);
  }
#pragma unroll
  for (int off = 32; off; off >>= 1) lmax = fmaxf(lmax, __shfl_down(lmax, off, 64));
  if ((t & 63) == 0) red[t >> 6] = lmax;
  __syncthreads();
  if (t == 0) red[4] = fmaxf(fmaxf(red[0], red[1]), fmaxf(red[2], red[3]));
  __syncthreads();
  const float m = red[4];
  __syncthreads();

  float lsum = 0.f;
#pragma unroll
  for (int j = 0; j < 4; ++j) {
    const int k = t + j * 256;
    float p = __expf(sc[k] - m);
    sc[k] = p;
    lsum += p;
  }
#pragma unroll
  for (int off = 32; off; off >>= 1) lsum += __shfl_down(lsum, off, 64);
  if ((t & 63) == 0) red[t >> 6] = lsum;
  __syncthreads();
  if (t == 0) red[4] = red[0] + red[1] + red[2] + red[3];
  __syncthreads();
  const float inv_l = 1.0f / red[4];

  // PV: thread (chunk, d)
  const int d = t & 63, chunk = t >> 6;
  const size_t vbase = (size_t)(b * SEQ) * (3 * DIM) + 2 * DIM + h * HDIM + d;
  float acc = 0.f;
  const int k0 = chunk * 256;
  for (int k = k0; k < k0 + 256; ++k) acc += sc[k] * qkv[vbase + (size_t)k * (3 * DIM)];
  opart[chunk][d] = acc;
  __syncthreads();
  if (t < HDIM) {
    float val = (opart[0][t] + opart[1][t] + opart[2][t] + opart[3][t]) * inv_l;
    o[(size_t)(b * SEQ + qi) * DIM + h * HDIM + t] = val;
  }
}

extern "C" void kernel_launch(void* const* d_in, const int* in_sizes, int n_in,
                              void* d_out, int out_size, void* d_ws, size_t ws_size,
                              hipStream_t stream) {
  const float* x      = (const float*)d_in[0];
  const float* ln1_s  = (const float*)d_in[1];
  const float* ln1_b  = (const float*)d_in[2];
  const float* qkv_w  = (const float*)d_in[3];
  const float* qkv_b  = (const float*)d_in[4];
  const float* proj_w = (const float*)d_in[5];
  const float* proj_b = (const float*)d_in[6];
  const float* ln2_s  = (const float*)d_in[7];
  const float* ln2_b  = (const float*)d_in[8];
  const float* fc1_w  = (const float*)d_in[9];
  const float* fc1_b  = (const float*)d_in[10];
  const float* fc2_w  = (const float*)d_in[11];
  const float* fc2_b  = (const float*)d_in[12];
  float* out = (float*)d_out;

  char* ws = (char*)d_ws;
  // bufA: qkv [8192,2304] (75.5MB) then hidden [8192,3072] (100.7MB)
  // bufB: y (25.2MB), later o, later y2
  // bufC: x1 (25.2MB)
  const size_t szA = (size_t)MTOK * HID * sizeof(float);   // 100.7 MB
  const size_t szB = (size_t)MTOK * DIM * sizeof(float);   // 25.2 MB
  float* bufA = (float*)(ws);
  float* bufB = (float*)(ws + szA);
  float* bufC = (float*)(ws + szA + szB);

  dim3 tb(16, 16);

  // 1) LN1: y = LN(x)
  ln_kernel<<<MTOK, 256, 0, stream>>>(x, ln1_s, ln1_b, bufB);
  // 2) QKV GEMM: qkv = y @ qkv_w + b   [8192,768]@[768,2304]
  gemm_kernel<0, false><<<dim3((3 * DIM) / 64, MTOK / 64), tb, 0, stream>>>(
      bufB, qkv_w, qkv_b, nullptr, bufA, MTOK, 3 * DIM, DIM);
  // 3) attention: o = softmax(QK^T)V  (overwrites bufB)
  attn_kernel<<<dim3(SEQ, BATCH * NHEAD), 256, 0, stream>>>(bufA, bufB);
  // 4) proj GEMM + residual: x1 = x + o@proj_w + b
  gemm_kernel<0, true><<<dim3(DIM / 64, MTOK / 64), tb, 0, stream>>>(
      bufB, proj_w, proj_b, x, bufC, MTOK, DIM, DIM);
  // 5) LN2: y2 = LN(x1)  (overwrites bufB)
  ln_kernel<<<MTOK, 256, 0, stream>>>(bufC, ln2_s, ln2_b, bufB);
  // 6) fc1 + gelu: h = gelu(y2 @ fc1_w + b)  [8192,768]@[768,3072]
  gemm_kernel<1, false><<<dim3(HID / 64, MTOK / 64), tb, 0, stream>>>(
      bufB, fc1_w, fc1_b, nullptr, bufA, MTOK, HID, DIM);
  // 7) fc2 + residual: out = x1 + h@fc2_w + b
  gemm_kernel<0, true><<<dim3(DIM / 64, MTOK / 64), tb, 0, stream>>>(
      bufA, fc2_w, fc2_b, bufC, out, MTOK, DIM, HID);
}

// Round 3
// 514.271 us; speedup vs baseline: 14.5771x; 14.5771x over previous
//
#include <hip/hip_runtime.h>
#include <hip/hip_bf16.h>
#include <math.h>

// TransformerBlock fp32 in/out; internal bf16 MFMA compute.
// B=8, N=1024, D=768, H=12, hd=64, HIDDEN=3072, EPS=1e-6

#define DIM 768
#define SEQ 1024
#define BATCH 8
#define NHEAD 12
#define HDIM 64
#define HID 3072
#define MTOK (BATCH * SEQ)  // 8192

typedef __attribute__((ext_vector_type(8))) short short8;
typedef __attribute__((ext_vector_type(4))) short short4v;
typedef __attribute__((ext_vector_type(4))) float floatx4;

__device__ __forceinline__ short f2s(float x) {
  __hip_bfloat16 h = __float2bfloat16(x);
  return __builtin_bit_cast(short, h);
}
__device__ __forceinline__ float s2f(short s) {
  return __bfloat162float(__builtin_bit_cast(__hip_bfloat16, s));
}
__device__ __forceinline__ floatx4 zf4() {
  floatx4 v; v[0] = v[1] = v[2] = v[3] = 0.f; return v;
}
__device__ __forceinline__ float gelu_f(float x) {
  float z = 0.7978845608028654f * (x + 0.044715f * x * x * x);
  float u = __expf(2.f * z);
  return 0.5f * x * (2.f - 2.f / (u + 1.f));
}

// ---------- weight transpose+convert: fp32 [K,N] -> bf16 [N,K] ----------
__global__ __launch_bounds__(256) void tr_kernel(const float* __restrict__ in,
                                                 short* __restrict__ out, int K, int N) {
  __shared__ float tile[32][33];
  const int tx = threadIdx.x, ty = threadIdx.y;
  const int n0 = blockIdx.x * 32, k0 = blockIdx.y * 32;
#pragma unroll
  for (int i = 0; i < 4; ++i)
    tile[ty + i * 8][tx] = in[(size_t)(k0 + ty + i * 8) * N + n0 + tx];
  __syncthreads();
#pragma unroll
  for (int i = 0; i < 4; ++i)
    out[(size_t)(n0 + ty + i * 8) * K + k0 + tx] = f2s(tile[tx][ty + i * 8]);
}

// ---------- LayerNorm: fp32 in -> bf16 out ----------
__global__ __launch_bounds__(256) void ln_kernel(const float* __restrict__ x,
                                                 const float* __restrict__ scale,
                                                 const float* __restrict__ bias,
                                                 short* __restrict__ y) {
  const int row = blockIdx.x;
  const int t = threadIdx.x;
  const float* xr = x + (size_t)row * DIM;
  float v[3];
  float s1 = 0.f, s2 = 0.f;
#pragma unroll
  for (int j = 0; j < 3; ++j) {
    v[j] = xr[t + j * 256];
    s1 += v[j];
    s2 += v[j] * v[j];
  }
#pragma unroll
  for (int off = 32; off; off >>= 1) {
    s1 += __shfl_down(s1, off, 64);
    s2 += __shfl_down(s2, off, 64);
  }
  __shared__ float r1[4], r2[4], bc[2];
  const int wave = t >> 6, lane = t & 63;
  if (lane == 0) { r1[wave] = s1; r2[wave] = s2; }
  __syncthreads();
  if (t == 0) {
    float S1 = r1[0] + r1[1] + r1[2] + r1[3];
    float S2 = r2[0] + r2[1] + r2[2] + r2[3];
    float mu = S1 * (1.0f / DIM);
    float var = S2 * (1.0f / DIM) - mu * mu;
    bc[0] = mu;
    bc[1] = rsqrtf(fmaxf(var, 0.f) + 1e-6f);
  }
  __syncthreads();
  const float mu = bc[0], rstd = bc[1];
#pragma unroll
  for (int j = 0; j < 3; ++j) {
    const int idx = t + j * 256;
    y[(size_t)row * DIM + idx] = f2s((v[j] - mu) * rstd * scale[idx] + bias[idx]);
  }
}

// ---------- async 16B global->LDS staging of a 128x32 bf16 tile, xor-swizzled ----------
// LDS slot S(16B) holds global (row = S>>2, chunk = (S&3) ^ ((row>>1)&3)).
__device__ __forceinline__ void stage_tile(const short* __restrict__ src, int ld,
                                           short* lds, int t) {
  const int lane = t & 63;
  const int w = t >> 6;
#pragma unroll
  for (int i = 0; i < 2; ++i) {
    const int S = w * 128 + i * 64 + lane;
    const int row = S >> 2;
    const int chunk = (S & 3) ^ ((row >> 1) & 3);
    const short* g = src + (size_t)row * ld + chunk * 8;
    const unsigned off = __builtin_amdgcn_readfirstlane((unsigned)((w * 128 + i * 64) * 16));
    __builtin_amdgcn_global_load_lds(
        (const __attribute__((address_space(1))) void*)g,
        (__attribute__((address_space(3))) void*)((char*)lds + off), 16, 0, 0);
  }
}

// ---------- MFMA GEMM: C[M,N] = A[M,K](bf16) @ Bt[N,K]^T(bf16) + bias ----------
// MODE 0: qkv split -> Qb/Kb [bh][1024][64], Vtb [bh][64][1024]
// MODE 1: fp32 out + fp32 residual
// MODE 2: bf16 out + gelu
template <int MODE>
__global__ __launch_bounds__(256) void gemm_mfma(
    const short* __restrict__ A, const short* __restrict__ Bt,
    const float* __restrict__ bias, const float* __restrict__ res,
    float* __restrict__ outF, short* __restrict__ outB,
    short* __restrict__ Qb, short* __restrict__ Kb, short* __restrict__ Vtb,
    int N, int K) {
  __shared__ __align__(16) short Asm[4096];
  __shared__ __align__(16) short Bsm[4096];
  const int t = threadIdx.x;
  const int lane = t & 63, w = t >> 6, quad = lane >> 4, l15 = lane & 15;
  const int m0 = blockIdx.y * 128, n0 = blockIdx.x * 128;
  const int mb = (w & 1) * 64, nb = (w >> 1) * 64;

  floatx4 acc[4][4];
#pragma unroll
  for (int mi = 0; mi < 4; ++mi)
#pragma unroll
    for (int ni = 0; ni < 4; ++ni) acc[mi][ni] = zf4();

  for (int kt = 0; kt < K; kt += 32) {
    __syncthreads();
    stage_tile(A + (size_t)m0 * K + kt, K, Asm, t);
    stage_tile(Bt + (size_t)n0 * K + kt, K, Bsm, t);
    __syncthreads();
    short8 a[4], b[4];
#pragma unroll
    for (int mi = 0; mi < 4; ++mi) {
      const int r = mb + mi * 16 + l15;
      a[mi] = *(const short8*)(Asm + r * 32 + (quad ^ ((r >> 1) & 3)) * 8);
    }
#pragma unroll
    for (int ni = 0; ni < 4; ++ni) {
      const int r = nb + ni * 16 + l15;
      b[ni] = *(const short8*)(Bsm + r * 32 + (quad ^ ((r >> 1) & 3)) * 8);
    }
#pragma unroll
    for (int mi = 0; mi < 4; ++mi)
#pragma unroll
      for (int ni = 0; ni < 4; ++ni)
        acc[mi][ni] = __builtin_amdgcn_mfma_f32_16x16x32_bf16(a[mi], b[ni], acc[mi][ni], 0, 0, 0);
  }

#pragma unroll
  for (int mi = 0; mi < 4; ++mi) {
    const int row0 = m0 + mb + mi * 16 + quad * 4;
#pragma unroll
    for (int ni = 0; ni < 4; ++ni) {
      const int col = n0 + nb + ni * 16 + l15;
      const float bv = bias[col];
      float v[4];
#pragma unroll
      for (int r = 0; r < 4; ++r) v[r] = acc[mi][ni][r] + bv;
      if (MODE == 0) {
        const int bb = row0 >> 10;
        const int s0 = row0 & 1023;
        if (col < 1536) {
          const int cc = (col < 768) ? col : col - 768;
          const int h = cc >> 6, d = cc & 63;
          short* dst = (col < 768 ? Qb : Kb) + (size_t)(bb * NHEAD + h) * SEQ * HDIM;
#pragma unroll
          for (int r = 0; r < 4; ++r) dst[(size_t)(s0 + r) * HDIM + d] = f2s(v[r]);
        } else {
          const int cc = col - 1536;
          const int h = cc >> 6, d = cc & 63;
          short4v pv;
#pragma unroll
          for (int r = 0; r < 4; ++r) pv[r] = f2s(v[r]);
          *(short4v*)(Vtb + ((size_t)(bb * NHEAD + h) * HDIM + d) * SEQ + s0) = pv;
        }
      } else if (MODE == 1) {
#pragma unroll
        for (int r = 0; r < 4; ++r) {
          const size_t idx = (size_t)(row0 + r) * N + col;
          outF[idx] = v[r] + res[idx];
        }
      } else {
#pragma unroll
        for (int r = 0; r < 4; ++r)
          outB[(size_t)(row0 + r) * N + col] = f2s(gelu_f(v[r]));
      }
    }
  }
}

// ---------- Flash attention, bf16 MFMA; block = (128 q-rows, one bh) ----------
__global__ __launch_bounds__(256) void attn_kernel(
    const short* __restrict__ Qb, const short* __restrict__ Kb,
    const short* __restrict__ Vtb, short* __restrict__ o) {
  __shared__ __align__(16) short Ks[8192];    // [128 kv][8 chunks swz]
  __shared__ __align__(16) short Vts[8192];   // [64 d][16 chunks swz]
  __shared__ __align__(16) short Ps[16384];   // [128 q][16 chunks swz]
  const int t = threadIdx.x;
  const int lane = t & 63, w = t >> 6, quad = lane >> 4, l15 = lane & 15;
  const int qt = blockIdx.x;   // 0..7
  const int bh = blockIdx.y;   // 0..95
  const int q0 = qt * 128;
  const size_t qkbase = (size_t)bh * SEQ * HDIM;
  const size_t vbase = (size_t)bh * HDIM * SEQ;

  // Q a-frags held in registers for the whole kernel
  short8 aq[2][2];
#pragma unroll
  for (int mi = 0; mi < 2; ++mi)
#pragma unroll
    for (int ks = 0; ks < 2; ++ks)
      aq[mi][ks] = *(const short8*)(Qb + qkbase +
                                    (size_t)(q0 + w * 32 + mi * 16 + l15) * HDIM +
                                    ks * 32 + quad * 8);

  floatx4 oacc[2][4];
  float m_st[2][4], l_st[2][4];
#pragma unroll
  for (int mi = 0; mi < 2; ++mi)
#pragma unroll
    for (int r = 0; r < 4; ++r) { m_st[mi][r] = -1e30f; l_st[mi][r] = 0.f; }
#pragma unroll
  for (int mi = 0; mi < 2; ++mi)
#pragma unroll
    for (int di = 0; di < 4; ++di) oacc[mi][di] = zf4();

  for (int k0 = 0; k0 < SEQ; k0 += 128) {
    __syncthreads();
    // stage K tile [128][64] with row-xor swizzle on 16B chunks
#pragma unroll
    for (int j = 0; j < 4; ++j) {
      const int S = j * 256 + t;
      const int r = S >> 3, c = S & 7;
      *(short8*)(Ks + (r * 8 + (c ^ (r & 7))) * 8) =
          *(const short8*)(Kb + qkbase + (size_t)(k0 + r) * HDIM + c * 8);
    }
    // stage Vt tile [64][128]
#pragma unroll
    for (int j = 0; j < 4; ++j) {
      const int S = j * 256 + t;
      const int r = S >> 4, c = S & 15;
      *(short8*)(Vts + (r * 16 + (c ^ (r & 15))) * 8) =
          *(const short8*)(Vtb + vbase + (size_t)r * SEQ + k0 + c * 8);
    }
    __syncthreads();

    // S = Q K^T  (wave w owns q-rows w*32..w*32+31)
    floatx4 sacc[2][8];
#pragma unroll
    for (int mi = 0; mi < 2; ++mi)
#pragma unroll
      for (int ni = 0; ni < 8; ++ni) sacc[mi][ni] = zf4();
#pragma unroll
    for (int ks = 0; ks < 2; ++ks)
#pragma unroll
      for (int ni = 0; ni < 8; ++ni) {
        const int r = ni * 16 + l15;
        const short8 bk = *(const short8*)(Ks + r * 64 + (((ks * 4 + quad) ^ (r & 7)) * 8));
#pragma unroll
        for (int mi = 0; mi < 2; ++mi)
          sacc[mi][ni] = __builtin_amdgcn_mfma_f32_16x16x32_bf16(aq[mi][ks], bk, sacc[mi][ni], 0, 0, 0);
      }
#pragma unroll
    for (int mi = 0; mi < 2; ++mi)
#pragma unroll
      for (int ni = 0; ni < 8; ++ni) sacc[mi][ni] *= 0.125f;

    // online softmax (rows live in quads: row = quad*4 + reg)
    float alpha[2][4];
#pragma unroll
    for (int mi = 0; mi < 2; ++mi)
#pragma unroll
      for (int r = 0; r < 4; ++r) {
        float mx = sacc[mi][0][r];
#pragma unroll
        for (int ni = 1; ni < 8; ++ni) mx = fmaxf(mx, sacc[mi][ni][r]);
#pragma unroll
        for (int msk = 1; msk < 16; msk <<= 1) mx = fmaxf(mx, __shfl_xor(mx, msk, 64));
        const float mn = fmaxf(m_st[mi][r], mx);
        alpha[mi][r] = __expf(m_st[mi][r] - mn);
        m_st[mi][r] = mn;
        float rs = 0.f;
        const int prow = w * 32 + mi * 16 + quad * 4 + r;
#pragma unroll
        for (int ni = 0; ni < 8; ++ni) {
          const float p = __expf(sacc[mi][ni][r] - mn);
          const short pb = f2s(p);
          const int chunk = ni * 2 + (l15 >> 3);
          Ps[prow * 128 + ((chunk ^ (prow & 15)) * 8) + (l15 & 7)] = pb;
          rs += s2f(pb);
        }
#pragma unroll
        for (int msk = 1; msk < 16; msk <<= 1) rs += __shfl_xor(rs, msk, 64);
        l_st[mi][r] = l_st[mi][r] * alpha[mi][r] + rs;
      }
#pragma unroll
    for (int mi = 0; mi < 2; ++mi)
#pragma unroll
      for (int di = 0; di < 4; ++di)
#pragma unroll
        for (int r = 0; r < 4; ++r) oacc[mi][di][r] *= alpha[mi][r];

    // O += P V   (P read back from LDS in A-layout; intra-wave, no barrier)
#pragma unroll
    for (int ks = 0; ks < 4; ++ks) {
      short8 ap[2];
#pragma unroll
      for (int mi = 0; mi < 2; ++mi) {
        const int r = (2 * w + mi) * 16 + l15;
        ap[mi] = *(const short8*)(Ps + r * 128 + (((ks * 4 + quad) ^ (r & 15)) * 8));
      }
#pragma unroll
      for (int di = 0; di < 4; ++di) {
        const int r = di * 16 + l15;
        const short8 bv = *(const short8*)(Vts + r * 128 + (((ks * 4 + quad) ^ (r & 15)) * 8));
#pragma unroll
        for (int mi = 0; mi < 2; ++mi)
          oacc[mi][di] = __builtin_amdgcn_mfma_f32_16x16x32_bf16(ap[mi], bv, oacc[mi][di], 0, 0, 0);
      }
    }
  }

  // epilogue: o[token][h*64+d] bf16
  const int bb = bh / NHEAD, hh = bh % NHEAD;
#pragma unroll
  for (int mi = 0; mi < 2; ++mi) {
    const int trow0 = bb * SEQ + q0 + w * 32 + mi * 16 + quad * 4;
#pragma unroll
    for (int di = 0; di < 4; ++di) {
      const int col = hh * HDIM + di * 16 + l15;
#pragma unroll
      for (int r = 0; r < 4; ++r)
        o[(size_t)(trow0 + r) * DIM + col] = f2s(oacc[mi][di][r] / l_st[mi][r]);
    }
  }
}

extern "C" void kernel_launch(void* const* d_in, const int* in_sizes, int n_in,
                              void* d_out, int out_size, void* d_ws, size_t ws_size,
                              hipStream_t stream) {
  const float* x      = (const float*)d_in[0];
  const float* ln1_s  = (const float*)d_in[1];
  const float* ln1_b  = (const float*)d_in[2];
  const float* qkv_w  = (const float*)d_in[3];
  const float* qkv_b  = (const float*)d_in[4];
  const float* proj_w = (const float*)d_in[5];
  const float* proj_b = (const float*)d_in[6];
  const float* ln2_s  = (const float*)d_in[7];
  const float* ln2_b  = (const float*)d_in[8];
  const float* fc1_w  = (const float*)d_in[9];
  const float* fc1_b  = (const float*)d_in[10];
  const float* fc2_w  = (const float*)d_in[11];
  const float* fc2_b  = (const float*)d_in[12];
  float* out = (float*)d_out;

  char* p = (char*)d_ws;
  short* wqt = (short*)p; p += (size_t)(3 * DIM) * DIM * 2;       // [2304][768]
  short* wpt = (short*)p; p += (size_t)DIM * DIM * 2;             // [768][768]
  short* w1t = (short*)p; p += (size_t)HID * DIM * 2;             // [3072][768]
  short* w2t = (short*)p; p += (size_t)DIM * HID * 2;             // [768][3072]
  short* y   = (short*)p; p += (size_t)MTOK * DIM * 2;            // ln1 out; reused as attn o
  short* Qb  = (short*)p; p += (size_t)MTOK * DIM * 2;            // also reused as ln2 out
  short* Kb  = (short*)p; p += (size_t)MTOK * DIM * 2;
  short* Vtb = (short*)p; p += (size_t)MTOK * DIM * 2;
  float* x1  = (float*)p; p += (size_t)MTOK * DIM * 4;
  short* h   = (short*)p; p += (size_t)MTOK * HID * 2;
  short* obuf = y;   // attn output reuses y
  short* y2   = Qb;  // ln2 output reuses Qb

  // weight transposes (fp32 [K,N] -> bf16 [N,K])
  tr_kernel<<<dim3((3 * DIM) / 32, DIM / 32), dim3(32, 8), 0, stream>>>(qkv_w, wqt, DIM, 3 * DIM);
  tr_kernel<<<dim3(DIM / 32, DIM / 32), dim3(32, 8), 0, stream>>>(proj_w, wpt, DIM, DIM);
  tr_kernel<<<dim3(HID / 32, DIM / 32), dim3(32, 8), 0, stream>>>(fc1_w, w1t, DIM, HID);
  tr_kernel<<<dim3(DIM / 32, HID / 32), dim3(32, 8), 0, stream>>>(fc2_w, w2t, HID, DIM);

  // 1) y = LN1(x)
  ln_kernel<<<MTOK, 256, 0, stream>>>(x, ln1_s, ln1_b, y);
  // 2) qkv gemm -> Qb/Kb/Vtb (per-head layouts)
  gemm_mfma<0><<<dim3((3 * DIM) / 128, MTOK / 128), 256, 0, stream>>>(
      y, wqt, qkv_b, nullptr, nullptr, nullptr, Qb, Kb, Vtb, 3 * DIM, DIM);
  // 3) attention -> obuf
  attn_kernel<<<dim3(SEQ / 128, BATCH * NHEAD), 256, 0, stream>>>(Qb, Kb, Vtb, obuf);
  // 4) x1 = x + obuf @ proj_w + b
  gemm_mfma<1><<<dim3(DIM / 128, MTOK / 128), 256, 0, stream>>>(
      obuf, wpt, proj_b, x, x1, nullptr, nullptr, nullptr, nullptr, DIM, DIM);
  // 5) y2 = LN2(x1)
  ln_kernel<<<MTOK, 256, 0, stream>>>(x1, ln2_s, ln2_b, y2);
  // 6) h = gelu(y2 @ fc1_w + b)
  gemm_mfma<2><<<dim3(HID / 128, MTOK / 128), 256, 0, stream>>>(
      y2, w1t, fc1_b, nullptr, nullptr, h, nullptr, nullptr, nullptr, HID, DIM);
  // 7) out = x1 + h @ fc2_w + b
  gemm_mfma<1><<<dim3(DIM / 128, MTOK / 128), 256, 0, stream>>>(
      h, w2t, fc2_b, x1, out, nullptr, nullptr, nullptr, nullptr, DIM, HID);
}

// Round 4
// 416.637 us; speedup vs baseline: 17.9931x; 1.2343x over previous
//
#include <hip/hip_runtime.h>
#include <hip/hip_bf16.h>
#include <math.h>

// TransformerBlock fp32 in/out; internal bf16 MFMA compute.
// B=8, N=1024, D=768, H=12, hd=64, HIDDEN=3072, EPS=1e-6

#define DIM 768
#define SEQ 1024
#define BATCH 8
#define NHEAD 12
#define HDIM 64
#define HID 3072
#define MTOK (BATCH * SEQ)  // 8192

typedef __attribute__((ext_vector_type(8))) short short8;
typedef __attribute__((ext_vector_type(4))) short short4v;
typedef __attribute__((ext_vector_type(4))) float floatx4;

__device__ __forceinline__ short f2s(float x) {
  __hip_bfloat16 h = __float2bfloat16(x);
  return __builtin_bit_cast(short, h);
}
__device__ __forceinline__ float s2f(short s) {
  return __bfloat162float(__builtin_bit_cast(__hip_bfloat16, s));
}
__device__ __forceinline__ floatx4 zf4() {
  floatx4 v; v[0] = v[1] = v[2] = v[3] = 0.f; return v;
}
__device__ __forceinline__ float gelu_f(float x) {
  float z = 0.7978845608028654f * (x + 0.044715f * x * x * x);
  float u = __expf(2.f * z);
  return 0.5f * x * (2.f - 2.f / (u + 1.f));
}

// ---------- weight transpose+convert: fp32 [K,N] -> bf16 [N,K] ----------
__global__ __launch_bounds__(256) void tr_kernel(const float* __restrict__ in,
                                                 short* __restrict__ out, int K, int N) {
  __shared__ float tile[32][33];
  const int tx = threadIdx.x, ty = threadIdx.y;
  const int n0 = blockIdx.x * 32, k0 = blockIdx.y * 32;
#pragma unroll
  for (int i = 0; i < 4; ++i)
    tile[ty + i * 8][tx] = in[(size_t)(k0 + ty + i * 8) * N + n0 + tx];
  __syncthreads();
#pragma unroll
  for (int i = 0; i < 4; ++i)
    out[(size_t)(n0 + ty + i * 8) * K + k0 + tx] = f2s(tile[tx][ty + i * 8]);
}

// ---------- LayerNorm: fp32 in -> bf16 out ----------
__global__ __launch_bounds__(256) void ln_kernel(const float* __restrict__ x,
                                                 const float* __restrict__ scale,
                                                 const float* __restrict__ bias,
                                                 short* __restrict__ y) {
  const int row = blockIdx.x;
  const int t = threadIdx.x;
  const float* xr = x + (size_t)row * DIM;
  float v[3];
  float s1 = 0.f, s2 = 0.f;
#pragma unroll
  for (int j = 0; j < 3; ++j) {
    v[j] = xr[t + j * 256];
    s1 += v[j];
    s2 += v[j] * v[j];
  }
#pragma unroll
  for (int off = 32; off; off >>= 1) {
    s1 += __shfl_down(s1, off, 64);
    s2 += __shfl_down(s2, off, 64);
  }
  __shared__ float r1[4], r2[4], bc[2];
  const int wave = t >> 6, lane = t & 63;
  if (lane == 0) { r1[wave] = s1; r2[wave] = s2; }
  __syncthreads();
  if (t == 0) {
    float S1 = r1[0] + r1[1] + r1[2] + r1[3];
    float S2 = r2[0] + r2[1] + r2[2] + r2[3];
    float mu = S1 * (1.0f / DIM);
    float var = S2 * (1.0f / DIM) - mu * mu;
    bc[0] = mu;
    bc[1] = rsqrtf(fmaxf(var, 0.f) + 1e-6f);
  }
  __syncthreads();
  const float mu = bc[0], rstd = bc[1];
#pragma unroll
  for (int j = 0; j < 3; ++j) {
    const int idx = t + j * 256;
    y[(size_t)row * DIM + idx] = f2s((v[j] - mu) * rstd * scale[idx] + bias[idx]);
  }
}

// ---------- async 16B global->LDS staging of a 128x32 bf16 tile, xor-swizzled ----------
__device__ __forceinline__ void stage_tile(const short* __restrict__ src, int ld,
                                           short* lds, int t) {
  const int lane = t & 63;
  const int w = t >> 6;
#pragma unroll
  for (int i = 0; i < 2; ++i) {
    const int S = w * 128 + i * 64 + lane;
    const int row = S >> 2;
    const int chunk = (S & 3) ^ ((row >> 1) & 3);
    const short* g = src + (size_t)row * ld + chunk * 8;
    const unsigned off = __builtin_amdgcn_readfirstlane((unsigned)((w * 128 + i * 64) * 16));
    __builtin_amdgcn_global_load_lds(
        (const __attribute__((address_space(1))) void*)g,
        (__attribute__((address_space(3))) void*)((char*)lds + off), 16, 0, 0);
  }
}

// ---------- MFMA GEMM: C[M,N] = A[M,K](bf16) @ Bt[N,K]^T(bf16) + bias ----------
template <int MODE>
__global__ __launch_bounds__(256) void gemm_mfma(
    const short* __restrict__ A, const short* __restrict__ Bt,
    const float* __restrict__ bias, const float* __restrict__ res,
    float* __restrict__ outF, short* __restrict__ outB,
    short* __restrict__ Qb, short* __restrict__ Kb, short* __restrict__ Vtb,
    int N, int K) {
  __shared__ __align__(16) short Asm[4096];
  __shared__ __align__(16) short Bsm[4096];
  const int t = threadIdx.x;
  const int lane = t & 63, w = t >> 6, quad = lane >> 4, l15 = lane & 15;
  const int m0 = blockIdx.y * 128, n0 = blockIdx.x * 128;
  const int mb = (w & 1) * 64, nb = (w >> 1) * 64;

  floatx4 acc[4][4];
#pragma unroll
  for (int mi = 0; mi < 4; ++mi)
#pragma unroll
    for (int ni = 0; ni < 4; ++ni) acc[mi][ni] = zf4();

  for (int kt = 0; kt < K; kt += 32) {
    __syncthreads();
    stage_tile(A + (size_t)m0 * K + kt, K, Asm, t);
    stage_tile(Bt + (size_t)n0 * K + kt, K, Bsm, t);
    __syncthreads();
    short8 a[4], b[4];
#pragma unroll
    for (int mi = 0; mi < 4; ++mi) {
      const int r = mb + mi * 16 + l15;
      a[mi] = *(const short8*)(Asm + r * 32 + (quad ^ ((r >> 1) & 3)) * 8);
    }
#pragma unroll
    for (int ni = 0; ni < 4; ++ni) {
      const int r = nb + ni * 16 + l15;
      b[ni] = *(const short8*)(Bsm + r * 32 + (quad ^ ((r >> 1) & 3)) * 8);
    }
#pragma unroll
    for (int mi = 0; mi < 4; ++mi)
#pragma unroll
      for (int ni = 0; ni < 4; ++ni)
        acc[mi][ni] = __builtin_amdgcn_mfma_f32_16x16x32_bf16(a[mi], b[ni], acc[mi][ni], 0, 0, 0);
  }

#pragma unroll
  for (int mi = 0; mi < 4; ++mi) {
    const int row0 = m0 + mb + mi * 16 + quad * 4;
#pragma unroll
    for (int ni = 0; ni < 4; ++ni) {
      const int col = n0 + nb + ni * 16 + l15;
      const float bv = bias[col];
      float v[4];
#pragma unroll
      for (int r = 0; r < 4; ++r) v[r] = acc[mi][ni][r] + bv;
      if (MODE == 0) {
        const int bb = row0 >> 10;
        const int s0 = row0 & 1023;
        if (col < 1536) {
          const int cc = (col < 768) ? col : col - 768;
          const int h = cc >> 6, d = cc & 63;
          short* dst = (col < 768 ? Qb : Kb) + (size_t)(bb * NHEAD + h) * SEQ * HDIM;
#pragma unroll
          for (int r = 0; r < 4; ++r) dst[(size_t)(s0 + r) * HDIM + d] = f2s(v[r]);
        } else {
          const int cc = col - 1536;
          const int h = cc >> 6, d = cc & 63;
          short4v pv;
#pragma unroll
          for (int r = 0; r < 4; ++r) pv[r] = f2s(v[r]);
          *(short4v*)(Vtb + ((size_t)(bb * NHEAD + h) * HDIM + d) * SEQ + s0) = pv;
        }
      } else if (MODE == 1) {
#pragma unroll
        for (int r = 0; r < 4; ++r) {
          const size_t idx = (size_t)(row0 + r) * N + col;
          outF[idx] = v[r] + res[idx];
        }
      } else {
#pragma unroll
        for (int r = 0; r < 4; ++r)
          outB[(size_t)(row0 + r) * N + col] = f2s(gelu_f(v[r]));
      }
    }
  }
}

// ---------- attention v2: S^T = K Q^T, O^T = V^T P^T; KT=64, double-buffered ----------
// Block: 128 q-rows of one bh; wave w owns q-cols [w*32, w*32+32).
__device__ __forceinline__ void stage64(const short* __restrict__ src, int ld,
                                        short* lds, int t) {
  const int lane = t & 63, w = t >> 6;
#pragma unroll
  for (int i = 0; i < 2; ++i) {
    const int S = w * 128 + i * 64 + lane;   // 0..511 slots (16B each)
    const int r = S >> 3, c0 = S & 7;
    const int c = c0 ^ (r & 7);
    const short* g = src + (size_t)r * ld + c * 8;
    const unsigned off = __builtin_amdgcn_readfirstlane((unsigned)((w * 128 + i * 64) * 16));
    __builtin_amdgcn_global_load_lds(
        (const __attribute__((address_space(1))) void*)g,
        (__attribute__((address_space(3))) void*)((char*)lds + off), 16, 0, 0);
  }
}

__global__ __launch_bounds__(256) void attn_kernel(
    const short* __restrict__ Qb, const short* __restrict__ Kb,
    const short* __restrict__ Vtb, short* __restrict__ o) {
  __shared__ __align__(16) short Ks[2][4096];   // [64 kv][8 chunks swz]
  __shared__ __align__(16) short Vts[2][4096];  // [64 d][8 chunks swz]
  __shared__ __align__(16) short Pt[8192];      // per-wave [32 q][64 kv] swz
  const int t = threadIdx.x;
  const int lane = t & 63, w = t >> 6, quad = lane >> 4, l15 = lane & 15;
  const int q0 = blockIdx.x * 128;
  const int bh = blockIdx.y;
  const size_t qkbase = (size_t)bh * SEQ * HDIM;
  const size_t vbase = (size_t)bh * HDIM * SEQ;
  short* ptw = Pt + w * 2048;

  // Q B-frags in registers for the whole kernel: B[n=q=l15][k=dh=quad*8+j]
  short8 bq[2][2];
#pragma unroll
  for (int mi = 0; mi < 2; ++mi)
#pragma unroll
    for (int ks = 0; ks < 2; ++ks)
      bq[mi][ks] = *(const short8*)(Qb + qkbase +
                                    (size_t)(q0 + w * 32 + mi * 16 + l15) * HDIM +
                                    ks * 32 + quad * 8);

  floatx4 oacc[4][2];   // [di][mi]: d = di*16+quad*4+r, q = w*32+mi*16+l15
  float m_st[2], l_st[2];
#pragma unroll
  for (int mi = 0; mi < 2; ++mi) { m_st[mi] = -1e30f; l_st[mi] = 0.f; }
#pragma unroll
  for (int di = 0; di < 4; ++di)
#pragma unroll
    for (int mi = 0; mi < 2; ++mi) oacc[di][mi] = zf4();

  stage64(Kb + qkbase, HDIM, Ks[0], t);
  stage64(Vtb + vbase, SEQ, Vts[0], t);

  for (int kt = 0; kt < 16; ++kt) {
    __syncthreads();   // drains own staging vmcnt; all waves' staging complete
    const int cur = kt & 1;
    if (kt < 15) {
      stage64(Kb + qkbase + (size_t)(kt + 1) * 64 * HDIM, HDIM, Ks[cur ^ 1], t);
      stage64(Vtb + vbase + (kt + 1) * 64, SEQ, Vts[cur ^ 1], t);
    }

    // S^T = K Q^T : sacc[ni][mi], kv = ni*16+quad*4+r, q = w*32+mi*16+l15
    floatx4 sacc[4][2];
#pragma unroll
    for (int ni = 0; ni < 4; ++ni)
#pragma unroll
      for (int mi = 0; mi < 2; ++mi) sacc[ni][mi] = zf4();
#pragma unroll
    for (int ks = 0; ks < 2; ++ks) {
      short8 ak[4];
#pragma unroll
      for (int ni = 0; ni < 4; ++ni) {
        const int r = ni * 16 + l15;
        ak[ni] = *(const short8*)(Ks[cur] + r * 64 + (((ks * 4 + quad) ^ (r & 7)) * 8));
      }
#pragma unroll
      for (int ni = 0; ni < 4; ++ni)
#pragma unroll
        for (int mi = 0; mi < 2; ++mi)
          sacc[ni][mi] = __builtin_amdgcn_mfma_f32_16x16x32_bf16(ak[ni], bq[mi][ks], sacc[ni][mi], 0, 0, 0);
    }

    // online softmax per q-column (q = l15 for all our regs)
    float alpha[2];
#pragma unroll
    for (int mi = 0; mi < 2; ++mi) {
      float mx = -1e30f;
#pragma unroll
      for (int ni = 0; ni < 4; ++ni)
#pragma unroll
        for (int r = 0; r < 4; ++r) mx = fmaxf(mx, sacc[ni][mi][r]);
      mx = fmaxf(mx, __shfl_xor(mx, 16, 64));
      mx = fmaxf(mx, __shfl_xor(mx, 32, 64));
      mx *= 0.125f;
      const float mn = fmaxf(m_st[mi], mx);
      alpha[mi] = __expf(m_st[mi] - mn);
      m_st[mi] = mn;
      float rs = 0.f;
      const int row = mi * 16 + l15;
      const int swz = (row & 7) ^ ((row & 8) >> 1);
#pragma unroll
      for (int ni = 0; ni < 4; ++ni) {
        short4v pk;
#pragma unroll
        for (int r = 0; r < 4; ++r) {
          const float p = __expf(sacc[ni][mi][r] * 0.125f - mn);
          rs += p;
          pk[r] = f2s(p);
        }
        const int c = ni * 2 + (quad >> 1);
        *(short4v*)(ptw + row * 64 + ((c ^ swz) * 8 + (quad & 1) * 4)) = pk;
      }
      rs += __shfl_xor(rs, 16, 64);
      rs += __shfl_xor(rs, 32, 64);
      l_st[mi] = l_st[mi] * alpha[mi] + rs;
    }
#pragma unroll
    for (int di = 0; di < 4; ++di)
#pragma unroll
      for (int mi = 0; mi < 2; ++mi)
#pragma unroll
        for (int r = 0; r < 4; ++r) oacc[di][mi][r] *= alpha[mi];

    // O^T += V^T P^T  (P read back per-wave, no barrier needed)
#pragma unroll
    for (int ks = 0; ks < 2; ++ks) {
      short8 bp[2];
#pragma unroll
      for (int mi = 0; mi < 2; ++mi) {
        const int row = mi * 16 + l15;
        const int swz = (row & 7) ^ ((row & 8) >> 1);
        bp[mi] = *(const short8*)(ptw + row * 64 + (((ks * 4 + quad) ^ swz) * 8));
      }
      short8 av[4];
#pragma unroll
      for (int di = 0; di < 4; ++di) {
        const int r = di * 16 + l15;
        av[di] = *(const short8*)(Vts[cur] + r * 64 + (((ks * 4 + quad) ^ (r & 7)) * 8));
      }
#pragma unroll
      for (int di = 0; di < 4; ++di)
#pragma unroll
        for (int mi = 0; mi < 2; ++mi)
          oacc[di][mi] = __builtin_amdgcn_mfma_f32_16x16x32_bf16(av[di], bp[mi], oacc[di][mi], 0, 0, 0);
    }
  }

  // epilogue: o[token][h*64+d], d = di*16+quad*4+r (4 consecutive -> b64 store)
  const int bb = bh / NHEAD, hh = bh % NHEAD;
  float inv[2];
#pragma unroll
  for (int mi = 0; mi < 2; ++mi) inv[mi] = 1.0f / l_st[mi];
#pragma unroll
  for (int di = 0; di < 4; ++di)
#pragma unroll
    for (int mi = 0; mi < 2; ++mi) {
      const int tok = bb * SEQ + q0 + w * 32 + mi * 16 + l15;
      const int d = hh * HDIM + di * 16 + quad * 4;
      short4v ov;
#pragma unroll
      for (int r = 0; r < 4; ++r) ov[r] = f2s(oacc[di][mi][r] * inv[mi]);
      *(short4v*)(o + (size_t)tok * DIM + d) = ov;
    }
}

extern "C" void kernel_launch(void* const* d_in, const int* in_sizes, int n_in,
                              void* d_out, int out_size, void* d_ws, size_t ws_size,
                              hipStream_t stream) {
  const float* x      = (const float*)d_in[0];
  const float* ln1_s  = (const float*)d_in[1];
  const float* ln1_b  = (const float*)d_in[2];
  const float* qkv_w  = (const float*)d_in[3];
  const float* qkv_b  = (const float*)d_in[4];
  const float* proj_w = (const float*)d_in[5];
  const float* proj_b = (const float*)d_in[6];
  const float* ln2_s  = (const float*)d_in[7];
  const float* ln2_b  = (const float*)d_in[8];
  const float* fc1_w  = (const float*)d_in[9];
  const float* fc1_b  = (const float*)d_in[10];
  const float* fc2_w  = (const float*)d_in[11];
  const float* fc2_b  = (const float*)d_in[12];
  float* out = (float*)d_out;

  char* p = (char*)d_ws;
  short* wqt = (short*)p; p += (size_t)(3 * DIM) * DIM * 2;
  short* wpt = (short*)p; p += (size_t)DIM * DIM * 2;
  short* w1t = (short*)p; p += (size_t)HID * DIM * 2;
  short* w2t = (short*)p; p += (size_t)DIM * HID * 2;
  short* y   = (short*)p; p += (size_t)MTOK * DIM * 2;
  short* Qb  = (short*)p; p += (size_t)MTOK * DIM * 2;
  short* Kb  = (short*)p; p += (size_t)MTOK * DIM * 2;
  short* Vtb = (short*)p; p += (size_t)MTOK * DIM * 2;
  float* x1  = (float*)p; p += (size_t)MTOK * DIM * 4;
  short* h   = (short*)p; p += (size_t)MTOK * HID * 2;
  short* obuf = y;
  short* y2   = Qb;

  tr_kernel<<<dim3((3 * DIM) / 32, DIM / 32), dim3(32, 8), 0, stream>>>(qkv_w, wqt, DIM, 3 * DIM);
  tr_kernel<<<dim3(DIM / 32, DIM / 32), dim3(32, 8), 0, stream>>>(proj_w, wpt, DIM, DIM);
  tr_kernel<<<dim3(HID / 32, DIM / 32), dim3(32, 8), 0, stream>>>(fc1_w, w1t, DIM, HID);
  tr_kernel<<<dim3(DIM / 32, HID / 32), dim3(32, 8), 0, stream>>>(fc2_w, w2t, HID, DIM);

  ln_kernel<<<MTOK, 256, 0, stream>>>(x, ln1_s, ln1_b, y);
  gemm_mfma<0><<<dim3((3 * DIM) / 128, MTOK / 128), 256, 0, stream>>>(
      y, wqt, qkv_b, nullptr, nullptr, nullptr, Qb, Kb, Vtb, 3 * DIM, DIM);
  attn_kernel<<<dim3(SEQ / 128, BATCH * NHEAD), 256, 0, stream>>>(Qb, Kb, Vtb, obuf);
  gemm_mfma<1><<<dim3(DIM / 128, MTOK / 128), 256, 0, stream>>>(
      obuf, wpt, proj_b, x, x1, nullptr, nullptr, nullptr, nullptr, DIM, DIM);
  ln_kernel<<<MTOK, 256, 0, stream>>>(x1, ln2_s, ln2_b, y2);
  gemm_mfma<2><<<dim3(HID / 128, MTOK / 128), 256, 0, stream>>>(
      y2, w1t, fc1_b, nullptr, nullptr, h, nullptr, nullptr, nullptr, HID, DIM);
  gemm_mfma<1><<<dim3(DIM / 128, MTOK / 128), 256, 0, stream>>>(
      h, w2t, fc2_b, x1, out, nullptr, nullptr, nullptr, nullptr, DIM, HID);
}

// Round 5
// 395.824 us; speedup vs baseline: 18.9392x; 1.0526x over previous
//
#include <hip/hip_runtime.h>
#include <hip/hip_bf16.h>
#include <math.h>

// TransformerBlock fp32 in/out; internal bf16 MFMA compute.
// B=8, N=1024, D=768, H=12, hd=64, HIDDEN=3072, EPS=1e-6

#define DIM 768
#define SEQ 1024
#define BATCH 8
#define NHEAD 12
#define HDIM 64
#define HID 3072
#define MTOK (BATCH * SEQ)  // 8192

typedef __attribute__((ext_vector_type(8))) short short8;
typedef __attribute__((ext_vector_type(4))) short short4v;
typedef __attribute__((ext_vector_type(4))) float floatx4;

__device__ __forceinline__ short f2s(float x) {
  __hip_bfloat16 h = __float2bfloat16(x);
  return __builtin_bit_cast(short, h);
}
__device__ __forceinline__ float s2f(short s) {
  return __bfloat162float(__builtin_bit_cast(__hip_bfloat16, s));
}
__device__ __forceinline__ floatx4 zf4() {
  floatx4 v; v[0] = v[1] = v[2] = v[3] = 0.f; return v;
}
__device__ __forceinline__ float gelu_f(float x) {
  float z = 0.7978845608028654f * (x + 0.044715f * x * x * x);
  float u = __expf(2.f * z);
  return 0.5f * x * (2.f - 2.f / (u + 1.f));
}

// ---------- merged weight transpose+convert: fp32 [K,N] -> bf16 [N,K] ----------
// tile ranges: qkv 0..1727 (72x24), proj ..2303 (24x24), fc1 ..4607 (96x24), fc2 ..6911 (24x96)
__global__ __launch_bounds__(256) void tr4_kernel(
    const float* __restrict__ w0, short* __restrict__ o0,
    const float* __restrict__ w1, short* __restrict__ o1,
    const float* __restrict__ w2, short* __restrict__ o2,
    const float* __restrict__ w3, short* __restrict__ o3) {
  __shared__ float tile[32][33];
  const int id = blockIdx.x;
  const float* in;
  short* out;
  int K, N, tid;
  if (id < 1728)      { in = w0; out = o0; K = DIM; N = 3 * DIM; tid = id; }
  else if (id < 2304) { in = w1; out = o1; K = DIM; N = DIM;     tid = id - 1728; }
  else if (id < 4608) { in = w2; out = o2; K = DIM; N = HID;     tid = id - 2304; }
  else                { in = w3; out = o3; K = HID; N = DIM;     tid = id - 4608; }
  const int ntx = N >> 5;
  const int n0 = (tid % ntx) * 32, k0 = (tid / ntx) * 32;
  const int tx = threadIdx.x & 31, ty = threadIdx.x >> 5;
#pragma unroll
  for (int i = 0; i < 4; ++i)
    tile[ty + i * 8][tx] = in[(size_t)(k0 + ty + i * 8) * N + n0 + tx];
  __syncthreads();
#pragma unroll
  for (int i = 0; i < 4; ++i)
    out[(size_t)(n0 + ty + i * 8) * K + k0 + tx] = f2s(tile[tx][ty + i * 8]);
}

// ---------- LayerNorm: fp32 in -> bf16 out ----------
__global__ __launch_bounds__(256) void ln_kernel(const float* __restrict__ x,
                                                 const float* __restrict__ scale,
                                                 const float* __restrict__ bias,
                                                 short* __restrict__ y) {
  const int row = blockIdx.x;
  const int t = threadIdx.x;
  const float* xr = x + (size_t)row * DIM;
  float v[3];
  float s1 = 0.f, s2 = 0.f;
#pragma unroll
  for (int j = 0; j < 3; ++j) {
    v[j] = xr[t + j * 256];
    s1 += v[j];
    s2 += v[j] * v[j];
  }
#pragma unroll
  for (int off = 32; off; off >>= 1) {
    s1 += __shfl_down(s1, off, 64);
    s2 += __shfl_down(s2, off, 64);
  }
  __shared__ float r1[4], r2[4], bc[2];
  const int wave = t >> 6, lane = t & 63;
  if (lane == 0) { r1[wave] = s1; r2[wave] = s2; }
  __syncthreads();
  if (t == 0) {
    float S1 = r1[0] + r1[1] + r1[2] + r1[3];
    float S2 = r2[0] + r2[1] + r2[2] + r2[3];
    float mu = S1 * (1.0f / DIM);
    float var = S2 * (1.0f / DIM) - mu * mu;
    bc[0] = mu;
    bc[1] = rsqrtf(fmaxf(var, 0.f) + 1e-6f);
  }
  __syncthreads();
  const float mu = bc[0], rstd = bc[1];
#pragma unroll
  for (int j = 0; j < 3; ++j) {
    const int idx = t + j * 256;
    y[(size_t)row * DIM + idx] = f2s((v[j] - mu) * rstd * scale[idx] + bias[idx]);
  }
}

// ---------- async 16B global->LDS staging of a ROWSx32 bf16 tile, xor-swizzled ----------
template <int ROWS>
__device__ __forceinline__ void stage(const short* __restrict__ src, int ld,
                                      short* lds, int t) {
  const int lane = t & 63, w = t >> 6;
  constexpr int ITER = ROWS / 64;  // slots = ROWS*4, threads = 256
#pragma unroll
  for (int i = 0; i < ITER; ++i) {
    const int S = w * (64 * ITER) + i * 64 + lane;
    const int row = S >> 2;
    const int chunk = (S & 3) ^ ((row >> 1) & 3);
    const short* g = src + (size_t)row * ld + chunk * 8;
    const unsigned off = __builtin_amdgcn_readfirstlane((unsigned)((w * (64 * ITER) + i * 64) * 16));
    __builtin_amdgcn_global_load_lds(
        (const __attribute__((address_space(1))) void*)g,
        (__attribute__((address_space(3))) void*)((char*)lds + off), 16, 0, 0);
  }
}

// ---------- MFMA GEMM: C[8192,N] = A[8192,K](bf16) @ Bt[N,K]^T(bf16) + bias ----------
// 128 x NT tile, double-buffered staging, XCD-aware swizzle.
// MODE 0: qkv split -> Qb/Kb [bh][1024][64], Vtb [bh][64][1024]   (NT=128)
// MODE 1: fp32 out + fp32 residual                                (NT=64)
// MODE 2: bf16 out + gelu                                         (NT=128)
template <int MODE, int NT>
__global__ __launch_bounds__(256) void gemm_mfma(
    const short* __restrict__ A, const short* __restrict__ Bt,
    const float* __restrict__ bias, const float* __restrict__ res,
    float* __restrict__ outF, short* __restrict__ outB,
    short* __restrict__ Qb, short* __restrict__ Kb, short* __restrict__ Vtb,
    int N, int K) {
  constexpr int NI = NT / 32;                     // n-tiles per wave
  __shared__ __align__(16) short Asm[2][4096];
  __shared__ __align__(16) short Bsm[2][NT * 32];
  const int t = threadIdx.x;
  const int lane = t & 63, w = t >> 6, quad = lane >> 4, l15 = lane & 15;

  // XCD-aware swizzle: one XCD keeps all n-tiles of an m-strip together.
  const int nbx = gridDim.x;
  const int lid = blockIdx.y * nbx + blockIdx.x;
  const int xcd = lid & 7, local = lid >> 3;
  const int m0 = ((local / nbx) * 8 + xcd) * 128;
  const int n0 = (local % nbx) * NT;
  const int mb = (w & 1) * 64, nb = (w >> 1) * (NT / 2);

  floatx4 acc[4][NI];
#pragma unroll
  for (int mi = 0; mi < 4; ++mi)
#pragma unroll
    for (int ni = 0; ni < NI; ++ni) acc[mi][ni] = zf4();

  stage<128>(A + (size_t)m0 * K, K, Asm[0], t);
  stage<NT>(Bt + (size_t)n0 * K, K, Bsm[0], t);

  const int nk = K >> 5;
  for (int kt = 0; kt < nk; ++kt) {
    __syncthreads();
    const int cur = kt & 1;
    if (kt + 1 < nk) {
      stage<128>(A + (size_t)m0 * K + (kt + 1) * 32, K, Asm[cur ^ 1], t);
      stage<NT>(Bt + (size_t)n0 * K + (kt + 1) * 32, K, Bsm[cur ^ 1], t);
    }
    short8 a[4], b[NI];
#pragma unroll
    for (int mi = 0; mi < 4; ++mi) {
      const int r = mb + mi * 16 + l15;
      a[mi] = *(const short8*)(Asm[cur] + r * 32 + (quad ^ ((r >> 1) & 3)) * 8);
    }
#pragma unroll
    for (int ni = 0; ni < NI; ++ni) {
      const int r = nb + ni * 16 + l15;
      b[ni] = *(const short8*)(Bsm[cur] + r * 32 + (quad ^ ((r >> 1) & 3)) * 8);
    }
#pragma unroll
    for (int mi = 0; mi < 4; ++mi)
#pragma unroll
      for (int ni = 0; ni < NI; ++ni)
        acc[mi][ni] = __builtin_amdgcn_mfma_f32_16x16x32_bf16(a[mi], b[ni], acc[mi][ni], 0, 0, 0);
  }

#pragma unroll
  for (int mi = 0; mi < 4; ++mi) {
    const int row0 = m0 + mb + mi * 16 + quad * 4;
#pragma unroll
    for (int ni = 0; ni < NI; ++ni) {
      const int col = n0 + nb + ni * 16 + l15;
      const float bv = bias[col];
      float v[4];
#pragma unroll
      for (int r = 0; r < 4; ++r) v[r] = acc[mi][ni][r] + bv;
      if (MODE == 0) {
        const int bb = row0 >> 10;
        const int s0 = row0 & 1023;
        if (col < 1536) {
          const int cc = (col < 768) ? col : col - 768;
          const int h = cc >> 6, d = cc & 63;
          short* dst = (col < 768 ? Qb : Kb) + (size_t)(bb * NHEAD + h) * SEQ * HDIM;
#pragma unroll
          for (int r = 0; r < 4; ++r) dst[(size_t)(s0 + r) * HDIM + d] = f2s(v[r]);
        } else {
          const int cc = col - 1536;
          const int h = cc >> 6, d = cc & 63;
          short4v pv;
#pragma unroll
          for (int r = 0; r < 4; ++r) pv[r] = f2s(v[r]);
          *(short4v*)(Vtb + ((size_t)(bb * NHEAD + h) * HDIM + d) * SEQ + s0) = pv;
        }
      } else if (MODE == 1) {
#pragma unroll
        for (int r = 0; r < 4; ++r) {
          const size_t idx = (size_t)(row0 + r) * N + col;
          outF[idx] = v[r] + res[idx];
        }
      } else {
#pragma unroll
        for (int r = 0; r < 4; ++r)
          outB[(size_t)(row0 + r) * N + col] = f2s(gelu_f(v[r]));
      }
    }
  }
}

// ---------- attention: S^T = K Q^T, O^T = V^T P^T; KT=64, double-buffered ----------
__device__ __forceinline__ void stage64(const short* __restrict__ src, int ld,
                                        short* lds, int t) {
  const int lane = t & 63, w = t >> 6;
#pragma unroll
  for (int i = 0; i < 2; ++i) {
    const int S = w * 128 + i * 64 + lane;
    const int r = S >> 3, c0 = S & 7;
    const int c = c0 ^ (r & 7);
    const short* g = src + (size_t)r * ld + c * 8;
    const unsigned off = __builtin_amdgcn_readfirstlane((unsigned)((w * 128 + i * 64) * 16));
    __builtin_amdgcn_global_load_lds(
        (const __attribute__((address_space(1))) void*)g,
        (__attribute__((address_space(3))) void*)((char*)lds + off), 16, 0, 0);
  }
}

__global__ __launch_bounds__(256) void attn_kernel(
    const short* __restrict__ Qb, const short* __restrict__ Kb,
    const short* __restrict__ Vtb, short* __restrict__ o) {
  __shared__ __align__(16) short Ks[2][4096];
  __shared__ __align__(16) short Vts[2][4096];
  __shared__ __align__(16) short Pt[8192];
  const int t = threadIdx.x;
  const int lane = t & 63, w = t >> 6, quad = lane >> 4, l15 = lane & 15;
  const int q0 = blockIdx.x * 128;
  const int bh = blockIdx.y;
  const size_t qkbase = (size_t)bh * SEQ * HDIM;
  const size_t vbase = (size_t)bh * HDIM * SEQ;
  short* ptw = Pt + w * 2048;

  short8 bq[2][2];
#pragma unroll
  for (int mi = 0; mi < 2; ++mi)
#pragma unroll
    for (int ks = 0; ks < 2; ++ks)
      bq[mi][ks] = *(const short8*)(Qb + qkbase +
                                    (size_t)(q0 + w * 32 + mi * 16 + l15) * HDIM +
                                    ks * 32 + quad * 8);

  floatx4 oacc[4][2];
  float m_st[2], l_st[2];
#pragma unroll
  for (int mi = 0; mi < 2; ++mi) { m_st[mi] = -1e30f; l_st[mi] = 0.f; }
#pragma unroll
  for (int di = 0; di < 4; ++di)
#pragma unroll
    for (int mi = 0; mi < 2; ++mi) oacc[di][mi] = zf4();

  stage64(Kb + qkbase, HDIM, Ks[0], t);
  stage64(Vtb + vbase, SEQ, Vts[0], t);

  for (int kt = 0; kt < 16; ++kt) {
    __syncthreads();
    const int cur = kt & 1;
    if (kt < 15) {
      stage64(Kb + qkbase + (size_t)(kt + 1) * 64 * HDIM, HDIM, Ks[cur ^ 1], t);
      stage64(Vtb + vbase + (kt + 1) * 64, SEQ, Vts[cur ^ 1], t);
    }

    floatx4 sacc[4][2];
#pragma unroll
    for (int ni = 0; ni < 4; ++ni)
#pragma unroll
      for (int mi = 0; mi < 2; ++mi) sacc[ni][mi] = zf4();
#pragma unroll
    for (int ks = 0; ks < 2; ++ks) {
      short8 ak[4];
#pragma unroll
      for (int ni = 0; ni < 4; ++ni) {
        const int r = ni * 16 + l15;
        ak[ni] = *(const short8*)(Ks[cur] + r * 64 + (((ks * 4 + quad) ^ (r & 7)) * 8));
      }
#pragma unroll
      for (int ni = 0; ni < 4; ++ni)
#pragma unroll
        for (int mi = 0; mi < 2; ++mi)
          sacc[ni][mi] = __builtin_amdgcn_mfma_f32_16x16x32_bf16(ak[ni], bq[mi][ks], sacc[ni][mi], 0, 0, 0);
    }

    float alpha[2];
#pragma unroll
    for (int mi = 0; mi < 2; ++mi) {
      float mx = -1e30f;
#pragma unroll
      for (int ni = 0; ni < 4; ++ni)
#pragma unroll
        for (int r = 0; r < 4; ++r) mx = fmaxf(mx, sacc[ni][mi][r]);
      mx = fmaxf(mx, __shfl_xor(mx, 16, 64));
      mx = fmaxf(mx, __shfl_xor(mx, 32, 64));
      mx *= 0.125f;
      const float mn = fmaxf(m_st[mi], mx);
      alpha[mi] = __expf(m_st[mi] - mn);
      m_st[mi] = mn;
      float rs = 0.f;
      const int row = mi * 16 + l15;
      const int swz = (row & 7) ^ ((row & 8) >> 1);
#pragma unroll
      for (int ni = 0; ni < 4; ++ni) {
        short4v pk;
#pragma unroll
        for (int r = 0; r < 4; ++r) {
          const float p = __expf(sacc[ni][mi][r] * 0.125f - mn);
          rs += p;
          pk[r] = f2s(p);
        }
        const int c = ni * 2 + (quad >> 1);
        *(short4v*)(ptw + row * 64 + ((c ^ swz) * 8 + (quad & 1) * 4)) = pk;
      }
      rs += __shfl_xor(rs, 16, 64);
      rs += __shfl_xor(rs, 32, 64);
      l_st[mi] = l_st[mi] * alpha[mi] + rs;
    }
#pragma unroll
    for (int di = 0; di < 4; ++di)
#pragma unroll
      for (int mi = 0; mi < 2; ++mi)
#pragma unroll
        for (int r = 0; r < 4; ++r) oacc[di][mi][r] *= alpha[mi];

#pragma unroll
    for (int ks = 0; ks < 2; ++ks) {
      short8 bp[2];
#pragma unroll
      for (int mi = 0; mi < 2; ++mi) {
        const int row = mi * 16 + l15;
        const int swz = (row & 7) ^ ((row & 8) >> 1);
        bp[mi] = *(const short8*)(ptw + row * 64 + (((ks * 4 + quad) ^ swz) * 8));
      }
      short8 av[4];
#pragma unroll
      for (int di = 0; di < 4; ++di) {
        const int r = di * 16 + l15;
        av[di] = *(const short8*)(Vts[cur] + r * 64 + (((ks * 4 + quad) ^ (r & 7)) * 8));
      }
#pragma unroll
      for (int di = 0; di < 4; ++di)
#pragma unroll
        for (int mi = 0; mi < 2; ++mi)
          oacc[di][mi] = __builtin_amdgcn_mfma_f32_16x16x32_bf16(av[di], bp[mi], oacc[di][mi], 0, 0, 0);
    }
  }

  const int bb = bh / NHEAD, hh = bh % NHEAD;
  float inv[2];
#pragma unroll
  for (int mi = 0; mi < 2; ++mi) inv[mi] = 1.0f / l_st[mi];
#pragma unroll
  for (int di = 0; di < 4; ++di)
#pragma unroll
    for (int mi = 0; mi < 2; ++mi) {
      const int tok = bb * SEQ + q0 + w * 32 + mi * 16 + l15;
      const int d = hh * HDIM + di * 16 + quad * 4;
      short4v ov;
#pragma unroll
      for (int r = 0; r < 4; ++r) ov[r] = f2s(oacc[di][mi][r] * inv[mi]);
      *(short4v*)(o + (size_t)tok * DIM + d) = ov;
    }
}

extern "C" void kernel_launch(void* const* d_in, const int* in_sizes, int n_in,
                              void* d_out, int out_size, void* d_ws, size_t ws_size,
                              hipStream_t stream) {
  const float* x      = (const float*)d_in[0];
  const float* ln1_s  = (const float*)d_in[1];
  const float* ln1_b  = (const float*)d_in[2];
  const float* qkv_w  = (const float*)d_in[3];
  const float* qkv_b  = (const float*)d_in[4];
  const float* proj_w = (const float*)d_in[5];
  const float* proj_b = (const float*)d_in[6];
  const float* ln2_s  = (const float*)d_in[7];
  const float* ln2_b  = (const float*)d_in[8];
  const float* fc1_w  = (const float*)d_in[9];
  const float* fc1_b  = (const float*)d_in[10];
  const float* fc2_w  = (const float*)d_in[11];
  const float* fc2_b  = (const float*)d_in[12];
  float* out = (float*)d_out;

  char* p = (char*)d_ws;
  short* wqt = (short*)p; p += (size_t)(3 * DIM) * DIM * 2;
  short* wpt = (short*)p; p += (size_t)DIM * DIM * 2;
  short* w1t = (short*)p; p += (size_t)HID * DIM * 2;
  short* w2t = (short*)p; p += (size_t)DIM * HID * 2;
  short* y   = (short*)p; p += (size_t)MTOK * DIM * 2;
  short* Qb  = (short*)p; p += (size_t)MTOK * DIM * 2;
  short* Kb  = (short*)p; p += (size_t)MTOK * DIM * 2;
  short* Vtb = (short*)p; p += (size_t)MTOK * DIM * 2;
  float* x1  = (float*)p; p += (size_t)MTOK * DIM * 4;
  short* h   = (short*)p; p += (size_t)MTOK * HID * 2;
  short* obuf = y;
  short* y2   = Qb;

  tr4_kernel<<<6912, 256, 0, stream>>>(qkv_w, wqt, proj_w, wpt, fc1_w, w1t, fc2_w, w2t);

  ln_kernel<<<MTOK, 256, 0, stream>>>(x, ln1_s, ln1_b, y);
  gemm_mfma<0, 128><<<dim3(18, 64), 256, 0, stream>>>(
      y, wqt, qkv_b, nullptr, nullptr, nullptr, Qb, Kb, Vtb, 3 * DIM, DIM);
  attn_kernel<<<dim3(SEQ / 128, BATCH * NHEAD), 256, 0, stream>>>(Qb, Kb, Vtb, obuf);
  gemm_mfma<1, 64><<<dim3(12, 64), 256, 0, stream>>>(
      obuf, wpt, proj_b, x, x1, nullptr, nullptr, nullptr, nullptr, DIM, DIM);
  ln_kernel<<<MTOK, 256, 0, stream>>>(x1, ln2_s, ln2_b, y2);
  gemm_mfma<2, 128><<<dim3(24, 64), 256, 0, stream>>>(
      y2, w1t, fc1_b, nullptr, nullptr, h, nullptr, nullptr, nullptr, HID, DIM);
  gemm_mfma<1, 64><<<dim3(12, 64), 256, 0, stream>>>(
      h, w2t, fc2_b, x1, out, nullptr, nullptr, nullptr, nullptr, DIM, HID);
}